// Round 11
// baseline (117.417 us; speedup 1.0000x reference)
//
#include <hip/hip_runtime.h>
#include <stdint.h>

// Problem dims (fixed): B=2, S=2048, D=1024, H=16, d_head=64
#define SEQ 2048
#define A_SIZE 4194304   // 2*2048*1024 floats (output 'a'), present follows

typedef short short8 __attribute__((ext_vector_type(8)));
typedef float f32x4 __attribute__((ext_vector_type(4)));

#define AS1 __attribute__((address_space(1)))
#define AS3 __attribute__((address_space(3)))

static __device__ __forceinline__ void async16(const void* g, void* l) {
  __builtin_amdgcn_global_load_lds((const AS1 uint32_t*)g, (AS3 uint32_t*)l, 16, 0, 0);
}

static __device__ __forceinline__ unsigned short f2bf(float f) {
  union { float f; uint32_t u; } v; v.f = f;
  uint32_t u = v.u;
  return (unsigned short)((u + 0x7FFFu + ((u >> 16) & 1u)) >> 16);
}

static __device__ __forceinline__ uint32_t fbits(float f) {
  union { float f; uint32_t u; } v; v.f = f;
  return v.u;
}

static __device__ __forceinline__ float bf2f(unsigned short b) {
  union { uint32_t u; float f; } c; c.u = ((uint32_t)b) << 16;
  return c.f;
}

// pack two floats to two truncated bf16 in one u32 (used for P in attn only)
static __device__ __forceinline__ uint32_t pack_bf2(float p0, float p1) {
  return __builtin_amdgcn_perm(fbits(p1), fbits(p0), 0x07060302u);
}

// RNE pack for GEMM outputs
static __device__ __forceinline__ uint32_t pack_rne(float a, float b) {
  return (uint32_t)f2bf(a) | ((uint32_t)f2bf(b) << 16);
}

// T-stage swizzle: m' = m ^ ((n>>3 & 7)<<3). Multiple of 8 => keeps 4- and
// 8-short runs contiguous; spreads the emit's d0-strided reads across banks.
#define TSWZ(n, m) ((m) ^ ((((n) >> 3) & 7) << 3))

// ---------------- combined prep: x->bf16, w_attn^T->bf16, w_proj^T->bf16 ----------------
static __device__ __forceinline__ void tcvt_body(const float* in, unsigned short* out,
                                                 int R, int C, int bx, int by,
                                                 unsigned short (*tile)[65]) {
  int c0 = bx * 64, r0 = by * 64;
  int tid = threadIdx.x;
  #pragma unroll
  for (int it = 0; it < 16; ++it) {
    int idx = it * 256 + tid;
    int r = idx >> 6, c = idx & 63;
    tile[r][c] = f2bf(in[(size_t)(r0 + r) * C + c0 + c]);
  }
  __syncthreads();
  #pragma unroll
  for (int it = 0; it < 16; ++it) {
    int idx = it * 256 + tid;
    int r = idx >> 6, c = idx & 63;
    out[(size_t)(c0 + r) * R + r0 + c] = tile[c][r];
  }
}

__global__ __launch_bounds__(256) void k_prep(
    const float* __restrict__ x, unsigned short* __restrict__ x_bf,
    const float* __restrict__ w_attn, unsigned short* __restrict__ waT,
    const float* __restrict__ w_proj, unsigned short* __restrict__ wpT) {
  __shared__ unsigned short tile[64][65];
  int bid = blockIdx.x;
  if (bid < 4096) {
    int i = bid * 256 + threadIdx.x;
    float4 f = ((const float4*)x)[i];
    ushort4 o;
    o.x = f2bf(f.x); o.y = f2bf(f.y); o.z = f2bf(f.z); o.w = f2bf(f.w);
    ((ushort4*)x_bf)[i] = o;
  } else if (bid < 4096 + 768) {
    int t = bid - 4096;
    tcvt_body(w_attn, waT, 1024, 3072, t % 48, t / 48, tile);
  } else {
    int t = bid - 4096 - 768;
    tcvt_body(w_proj, wpT, 1024, 1024, t % 16, t / 16, tile);
  }
}

// ---------------- QKV GEMM: C[4096,3072] = A[4096,1024] * BT[3072,1024]^T + bias ----
// BK=64 (half the barriers of BK=32), staging XOR-swizzled (c' = c ^ (row&7),
// pre-swizzled global source, 2-way on read = free). T-stage ALIASES the
// staging LDS (used only after the K-loop) -> 35KB block footprint -> 4 blocks/CU.
__global__ __launch_bounds__(256) void k_gemm_qkv(
    const unsigned short* __restrict__ A,
    const unsigned short* __restrict__ BT,
    const float* __restrict__ bias,
    float* __restrict__ outp,          // d_out base; present at +A_SIZE
    unsigned short* __restrict__ q_ws,
    unsigned short* __restrict__ kp,
    unsigned short* __restrict__ vp) {
  const int K = 1024;
  __shared__ unsigned short smem[128 * 136];   // 34.8KB: staging (32KB) then T
  unsigned short* Asm = smem;                  // 128 x 64
  unsigned short* Bsm = smem + 128 * 64;       // 128 x 64
  unsigned short* T = smem;                    // 128 x 136 (post-loop)
  int tid = threadIdx.x;
  int lane = tid & 63, w = tid >> 6;
  int g = lane >> 4, qi = lane & 15;
  int wr = w >> 1, wc = w & 1;
  int bm = blockIdx.x & 31, bn = blockIdx.x >> 5;
  const unsigned short* Ag = A + (size_t)bm * 128 * K;
  const unsigned short* Bg = BT + (size_t)bn * 128 * K;
  f32x4 acc[4][4] = {};
  for (int kt = 0; kt < K; kt += 64) {
    #pragma unroll
    for (int i = 0; i < 4; ++i) {
      int j = i * 256 + tid;              // 0..1023: row = j>>3, slot = j&7
      int row = j >> 3, cp = j & 7;
      int cg = cp ^ (row & 7);            // pre-swizzled source chunk
      async16(Ag + (size_t)row * K + kt + cg * 8,
              (char*)Asm + (size_t)(i * 256 + w * 64) * 16);
      async16(Bg + (size_t)row * K + kt + cg * 8,
              (char*)Bsm + (size_t)(i * 256 + w * 64) * 16);
    }
    __syncthreads();
    #pragma unroll
    for (int kk = 0; kk < 2; ++kk) {
      short8 af[4], bf[4];
      #pragma unroll
      for (int mi = 0; mi < 4; ++mi)
        af[mi] = *(const short8*)&Asm[(wr * 64 + mi * 16 + qi) * 64 + (((kk * 4 + g) ^ (qi & 7)) * 8)];
      #pragma unroll
      for (int ni = 0; ni < 4; ++ni)
        bf[ni] = *(const short8*)&Bsm[(wc * 64 + ni * 16 + qi) * 64 + (((kk * 4 + g) ^ (qi & 7)) * 8)];
      #pragma unroll
      for (int mi = 0; mi < 4; ++mi)
        #pragma unroll
        for (int ni = 0; ni < 4; ++ni)
          acc[mi][ni] = __builtin_amdgcn_mfma_f32_16x16x32_bf16(af[mi], bf[ni], acc[mi][ni], 0, 0, 0);
    }
    __syncthreads();
  }
  // ---- stage C col-major: T[n][m'] (aliases staging LDS; all reads done) ----
  {
    int n0l = wc * 64, m0l = wr * 64;
    #pragma unroll
    for (int ni = 0; ni < 4; ++ni) {
      int nl = n0l + ni * 16 + qi;
      float bv = bias[bn * 128 + nl];
      #pragma unroll
      for (int mi = 0; mi < 4; ++mi) {
        int ml = m0l + mi * 16 + g * 4;
        uint2 pk;
        pk.x = pack_rne(acc[mi][ni][0] + bv, acc[mi][ni][1] + bv);
        pk.y = pack_rne(acc[mi][ni][2] + bv, acc[mi][ni][3] + bv);
        *(uint2*)&T[nl * 136 + TSWZ(nl, ml)] = pk;
      }
    }
  }
  __syncthreads();
  // ---- coalesced emit ----
  int third = bn >> 3;
  int b = bm >> 4;
  int s_base = (bm & 15) * 128;
  if (third == 0) {
    #pragma unroll
    for (int it = 0; it < 8; ++it) {
      int idx = it * 256 + tid;
      int sl = idx >> 4, d0 = idx & 15;
      unsigned short vv[8];
      #pragma unroll
      for (int jj = 0; jj < 8; ++jj) {
        int n = d0 * 8 + jj;
        vv[jj] = T[n * 136 + TSWZ(n, sl)];
      }
      int h = bn * 2 + (d0 >> 3);
      int din = (d0 & 7) * 8;
      *(short8*)&q_ws[(((size_t)(b * 16 + h)) * SEQ + s_base + sl) * 64 + din] = *(short8*)vv;
    }
  } else if (third == 1) {
    #pragma unroll
    for (int it = 0; it < 8; ++it) {
      int idx = it * 256 + tid;
      int sl = idx >> 4, d0 = idx & 15;
      unsigned short vv[8];
      #pragma unroll
      for (int jj = 0; jj < 8; ++jj) {
        int n = d0 * 8 + jj;
        vv[jj] = T[n * 136 + TSWZ(n, sl)];
      }
      int h = (bn - 8) * 2 + (d0 >> 3);
      int din = (d0 & 7) * 8;
      int sg = s_base + sl;
      // present[b][0][h] (fp32)
      float* pb = &outp[A_SIZE + ((((size_t)(b * 32 + h)) * SEQ + sg) * 64 + din)];
      float4 f0, f1;
      f0.x = bf2f(vv[0]); f0.y = bf2f(vv[1]); f0.z = bf2f(vv[2]); f0.w = bf2f(vv[3]);
      f1.x = bf2f(vv[4]); f1.y = bf2f(vv[5]); f1.z = bf2f(vv[6]); f1.w = bf2f(vv[7]);
      *(float4*)&pb[0] = f0;
      *(float4*)&pb[4] = f1;
      // kp fragment-packed
      int ks = sg & 63, tile = sg >> 6;
      int st = ((ks >> 5) << 1) | ((ks >> 2) & 1);
      int qik = (((ks >> 3) & 3) << 2) | (ks & 3);
      int jK = st * 2 + (din >> 5);
      int laneK = ((din >> 3) & 3) * 16 + qik;
      *(short8*)&kp[((((size_t)(b * 16 + h)) * 32 + tile) * 8 + jK) * 512 + laneK * 8] = *(short8*)vv;
    }
  } else {
    // vp: contiguous b128 LDS reads (key-runs stay contiguous under TSWZ) -> 16B stores
    #pragma unroll
    for (int it = 0; it < 8; ++it) {
      int idx = it * 256 + tid;
      int dcol = idx >> 4, k8 = idx & 15;
      short8 vv = *(const short8*)&T[dcol * 136 + TSWZ(dcol, k8 * 8)];
      int h = (bn - 16) * 2 + (dcol >> 6);
      int d = dcol & 63;
      int sg = s_base + k8 * 8;
      int tile = sg >> 6, ks0 = sg & 63;
      int jV = (d >> 4) * 2 + (ks0 >> 5);
      int laneV = ((ks0 >> 3) & 3) * 16 + (d & 15);
      *(short8*)&vp[((((size_t)(b * 16 + h)) * 32 + tile) * 8 + jV) * 512 + laneV * 8] = vv;
    }
    // present[b][1][h] (fp32)
    #pragma unroll
    for (int it = 0; it < 8; ++it) {
      int idx = it * 256 + tid;
      int sl = idx >> 4, d0 = idx & 15;
      unsigned short vv[8];
      #pragma unroll
      for (int jj = 0; jj < 8; ++jj) {
        int n = d0 * 8 + jj;
        vv[jj] = T[n * 136 + TSWZ(n, sl)];
      }
      int h = (bn - 16) * 2 + (d0 >> 3);
      int din = (d0 & 7) * 8;
      int sg = s_base + sl;
      float* pb = &outp[A_SIZE + ((((size_t)(b * 32 + 16 + h)) * SEQ + sg) * 64 + din)];
      float4 f0, f1;
      f0.x = bf2f(vv[0]); f0.y = bf2f(vv[1]); f0.z = bf2f(vv[2]); f0.w = bf2f(vv[3]);
      f1.x = bf2f(vv[4]); f1.y = bf2f(vv[5]); f1.z = bf2f(vv[6]); f1.w = bf2f(vv[7]);
      *(float4*)&pb[0] = f0;
      *(float4*)&pb[4] = f1;
    }
  }
}

// ---------------- proj GEMM: 64x64 tiles, 1024 blocks (4 blocks/CU, 16 waves/CU) ----
// Swapped orientation -> float4 stores. Wave grid 2x2, each wave 32x32.
__global__ __launch_bounds__(256) void k_gemm_proj(
    const unsigned short* __restrict__ A,
    const unsigned short* __restrict__ BT,
    const float* __restrict__ bias,
    float* __restrict__ outp) {
  const int K = 1024;
  __shared__ unsigned short Asm[64 * 32];
  __shared__ unsigned short Bsm[64 * 32];
  int tid = threadIdx.x;
  int lane = tid & 63, w = tid >> 6;
  int g = lane >> 4, qi = lane & 15;
  int wr = w >> 1, wc = w & 1;
  int bm = blockIdx.x & 63, bn = blockIdx.x >> 6;   // 64 x 16 tiles
  const unsigned short* Ag = A + (size_t)bm * 64 * K;
  const unsigned short* Bg = BT + (size_t)bn * 64 * K;
  f32x4 acc[2][2] = {};
  int row_s = tid >> 2, cp_s = tid & 3;
  int cg_s = cp_s ^ (row_s & 3);
  for (int kt = 0; kt < K; kt += 32) {
    async16(Ag + (size_t)row_s * K + kt + cg_s * 8, (char*)Asm + (size_t)tid * 16);
    async16(Bg + (size_t)row_s * K + kt + cg_s * 8, (char*)Bsm + (size_t)tid * 16);
    __syncthreads();
    short8 af[2], bf[2];
    #pragma unroll
    for (int mi = 0; mi < 2; ++mi)
      af[mi] = *(const short8*)&Asm[(wr * 32 + mi * 16 + qi) * 32 + ((g ^ (qi & 3)) * 8)];
    #pragma unroll
    for (int ni = 0; ni < 2; ++ni)
      bf[ni] = *(const short8*)&Bsm[(wc * 32 + ni * 16 + qi) * 32 + ((g ^ (qi & 3)) * 8)];
    #pragma unroll
    for (int mi = 0; mi < 2; ++mi)
      #pragma unroll
      for (int ni = 0; ni < 2; ++ni)
        acc[mi][ni] = __builtin_amdgcn_mfma_f32_16x16x32_bf16(bf[ni], af[mi], acc[mi][ni], 0, 0, 0);
    __syncthreads();
  }
  #pragma unroll
  for (int ni = 0; ni < 2; ++ni) {
    int n = bn * 64 + wc * 32 + ni * 16 + g * 4;
    float4 bv = *(const float4*)&bias[n];
    #pragma unroll
    for (int mi = 0; mi < 2; ++mi) {
      int m = bm * 64 + wr * 32 + mi * 16 + qi;
      float4 pf;
      pf.x = acc[mi][ni][0] + bv.x; pf.y = acc[mi][ni][1] + bv.y;
      pf.z = acc[mi][ni][2] + bv.z; pf.w = acc[mi][ni][3] + bv.w;
      *(float4*)&outp[(size_t)m * 1024 + n] = pf;
    }
  }
}

// ---------------- flash attention (causal), packed-fragment loads ----------------
#define CSC 0.18033688f   /* 0.125 * log2(e) */
__global__ __launch_bounds__(512, 4) void k_attn(
    const unsigned short* __restrict__ q_ws,
    const unsigned short* __restrict__ kp,
    const unsigned short* __restrict__ vp,
    unsigned short* __restrict__ a_out) {
  int bid = blockIdx.x;
  int xcd = bid & 7;
  int jb = bid >> 3;                 // 0..63
  int bh = xcd * 4 + (jb & 3);       // 4 heads per XCD -> K/V L2-resident
  int pairidx = jb >> 2;             // 0..15
  int tid = threadIdx.x, lane = tid & 63, w = tid >> 6;
  int g = lane >> 4, qi = lane & 15;
  int tilesel = w >> 2, wl = w & 3;
  int q0 = (tilesel ? pairidx : (31 - pairidx)) * 64;
  int qw = q0 + wl * 16;
  int qrow = qw + qi;
  const unsigned short* Qb = q_ws + (size_t)bh * SEQ * 64;
  const unsigned short* Kp = kp + (size_t)bh * SEQ * 64;   // 32 tiles * 4096 shorts
  const unsigned short* Vp = vp + (size_t)bh * SEQ * 64;

  short8 qf0 = *(const short8*)&Qb[(size_t)qrow * 64 + g * 8];
  short8 qf1 = *(const short8*)&Qb[(size_t)qrow * 64 + g * 8 + 32];

  f32x4 oacc[4] = {};
  float m2 = -1.0e30f, l_run = 0.f;   // per-lane partial sum over this lane's keys
  f32x4 z = {};
  int nfull = qw >> 6;

  for (int t = 0; t <= nfull; ++t) {
    const unsigned short* Kt = Kp + (size_t)t * 4096;
    const unsigned short* Vt = Vp + (size_t)t * 4096;
    // 16 contiguous 1KB wave loads
    short8 kf[4][2];
    #pragma unroll
    for (int st = 0; st < 4; ++st) {
      kf[st][0] = *(const short8*)&Kt[(st * 2 + 0) * 512 + lane * 8];
      kf[st][1] = *(const short8*)&Kt[(st * 2 + 1) * 512 + lane * 8];
    }
    short8 vf0[4], vf1[4];
    #pragma unroll
    for (int dt = 0; dt < 4; ++dt) {
      vf0[dt] = *(const short8*)&Vt[(dt * 2 + 0) * 512 + lane * 8];
      vf1[dt] = *(const short8*)&Vt[(dt * 2 + 1) * 512 + lane * 8];
    }
    f32x4 sa[4];
    #pragma unroll
    for (int st = 0; st < 4; ++st) {
      sa[st] = __builtin_amdgcn_mfma_f32_16x16x32_bf16(kf[st][0], qf0, z, 0, 0, 0);
      sa[st] = __builtin_amdgcn_mfma_f32_16x16x32_bf16(kf[st][1], qf1, sa[st], 0, 0, 0);
    }
    // lane (g,qi): sa[st][r] = score for q-row qrow, key t*64+(st>>1)*32+(st&1)*4+g*8+r
    float tm = -1.0e30f;
    if (t == nfull) {   // wave-uniform masked tail tile
      #pragma unroll
      for (int st = 0; st < 4; ++st)
        #pragma unroll
        for (int r = 0; r < 4; ++r) {
          int key = t * 64 + (st >> 1) * 32 + (st & 1) * 4 + g * 8 + r;
          float v = (key <= qrow) ? sa[st][r] * CSC : -1.0e30f;
          sa[st][r] = v;
          tm = fmaxf(tm, v);
        }
    } else {
      #pragma unroll
      for (int st = 0; st < 4; ++st)
        #pragma unroll
        for (int r = 0; r < 4; ++r) {
          sa[st][r] *= CSC;
          tm = fmaxf(tm, sa[st][r]);
        }
    }
    if (!__all(tm - m2 <= 4.0f)) {      // defer-max (partial-max bound suffices)
      tm = fmaxf(tm, __shfl_xor(tm, 16, 64));
      tm = fmaxf(tm, __shfl_xor(tm, 32, 64));
      float mn = fmaxf(m2, tm);
      float alpha = exp2f(m2 - mn);
      l_run *= alpha;
      #pragma unroll
      for (int dt = 0; dt < 4; ++dt)
        #pragma unroll
        for (int r = 0; r < 4; ++r) oacc[dt][r] *= alpha;
      m2 = mn;
    }
    float ps = 0.f;
    union { uint32_t u[4]; short8 s; } pb0, pb1;
    #pragma unroll
    for (int st = 0; st < 4; ++st) {
      float p0 = exp2f(sa[st][0] - m2);
      float p1 = exp2f(sa[st][1] - m2);
      float p2 = exp2f(sa[st][2] - m2);
      float p3 = exp2f(sa[st][3] - m2);
      ps += (p0 + p1) + (p2 + p3);
      uint32_t lo = pack_bf2(p0, p1), hi = pack_bf2(p2, p3);
      if (st < 2) { pb0.u[st * 2] = lo; pb0.u[st * 2 + 1] = hi; }
      else        { pb1.u[(st - 2) * 2] = lo; pb1.u[(st - 2) * 2 + 1] = hi; }
    }
    l_run += ps;
    #pragma unroll
    for (int dt = 0; dt < 4; ++dt) {
      oacc[dt] = __builtin_amdgcn_mfma_f32_16x16x32_bf16(vf0[dt], pb0.s, oacc[dt], 0, 0, 0);
      oacc[dt] = __builtin_amdgcn_mfma_f32_16x16x32_bf16(vf1[dt], pb1.s, oacc[dt], 0, 0, 0);
    }
  }

  // one-time l reduce across the 4 lane-groups of each q-row
  l_run += __shfl_xor(l_run, 16, 64);
  l_run += __shfl_xor(l_run, 32, 64);
  float inv = 1.0f / l_run;
  int b = bh >> 4, h = bh & 15;
  size_t rowbase = ((size_t)(b * SEQ + qw + qi)) * 1024 + h * 64;
  #pragma unroll
  for (int dt = 0; dt < 4; ++dt) {
    ushort4 o;
    o.x = f2bf(oacc[dt][0] * inv);
    o.y = f2bf(oacc[dt][1] * inv);
    o.z = f2bf(oacc[dt][2] * inv);
    o.w = f2bf(oacc[dt][3] * inv);
    *(ushort4*)&a_out[rowbase + dt * 16 + g * 4] = o;
  }
}

// ---------------- launch ----------------
extern "C" void kernel_launch(void* const* d_in, const int* in_sizes, int n_in,
                              void* d_out, int out_size, void* d_ws, size_t ws_size,
                              hipStream_t stream) {
  const float* x      = (const float*)d_in[0];
  const float* w_attn = (const float*)d_in[1];
  const float* b_attn = (const float*)d_in[2];
  const float* w_proj = (const float*)d_in[3];
  const float* b_proj = (const float*)d_in[4];
  float* out = (float*)d_out;
  char* ws = (char*)d_ws;
  // ws layout (48 MB total)
  unsigned short* x_bf = (unsigned short*)(ws);               //  8 MB
  unsigned short* waT  = (unsigned short*)(ws + 8388608);     //  6 MB
  unsigned short* wpT  = (unsigned short*)(ws + 14680064);    //  2 MB
  unsigned short* q_ws = (unsigned short*)(ws + 16777216);    //  8 MB
  unsigned short* kp   = (unsigned short*)(ws + 25165824);    //  8 MB (fragment-packed K)
  unsigned short* vp   = (unsigned short*)(ws + 33554432);    //  8 MB (fragment-packed V)
  unsigned short* a_ws = (unsigned short*)(ws + 41943040);    //  8 MB

  hipLaunchKernelGGL(k_prep, dim3(4096 + 768 + 256), dim3(256), 0, stream,
                     x, x_bf, w_attn, waT, w_proj, wpT);
  hipLaunchKernelGGL(k_gemm_qkv, dim3(768), dim3(256), 0, stream,
                     x_bf, waT, b_attn, out, q_ws, kp, vp);
  hipLaunchKernelGGL(k_attn, dim3(512), dim3(512), 0, stream, q_ws, kp, vp, a_ws);
  hipLaunchKernelGGL(k_gemm_proj, dim3(1024), dim3(256), 0, stream, a_ws, wpT, b_proj, out);
}

// Round 12
// 106.560 us; speedup vs baseline: 1.1019x; 1.1019x over previous
//
#include <hip/hip_runtime.h>
#include <stdint.h>

// Problem dims (fixed): B=2, S=2048, D=1024, H=16, d_head=64
#define SEQ 2048
#define A_SIZE 4194304   // 2*2048*1024 floats (output 'a'), present follows

typedef short short8 __attribute__((ext_vector_type(8)));
typedef float f32x4 __attribute__((ext_vector_type(4)));

#define AS1 __attribute__((address_space(1)))
#define AS3 __attribute__((address_space(3)))

static __device__ __forceinline__ void async16(const void* g, void* l) {
  __builtin_amdgcn_global_load_lds((const AS1 uint32_t*)g, (AS3 uint32_t*)l, 16, 0, 0);
}

static __device__ __forceinline__ unsigned short f2bf(float f) {
  union { float f; uint32_t u; } v; v.f = f;
  uint32_t u = v.u;
  return (unsigned short)((u + 0x7FFFu + ((u >> 16) & 1u)) >> 16);
}

static __device__ __forceinline__ uint32_t fbits(float f) {
  union { float f; uint32_t u; } v; v.f = f;
  return v.u;
}

static __device__ __forceinline__ float bf2f(unsigned short b) {
  union { uint32_t u; float f; } c; c.u = ((uint32_t)b) << 16;
  return c.f;
}

// pack two floats to two truncated bf16 in one u32 (used for P in attn only)
static __device__ __forceinline__ uint32_t pack_bf2(float p0, float p1) {
  return __builtin_amdgcn_perm(fbits(p1), fbits(p0), 0x07060302u);
}

// RNE pack for GEMM outputs
static __device__ __forceinline__ uint32_t pack_rne(float a, float b) {
  return (uint32_t)f2bf(a) | ((uint32_t)f2bf(b) << 16);
}

// T-stage swizzle: m' = m ^ ((n>>3 & 7)<<3). Multiple of 8 => keeps 4- and
// 8-short runs contiguous; spreads the emit's d0-strided reads across banks.
#define TSWZ(n, m) ((m) ^ ((((n) >> 3) & 7) << 3))

// ---------------- combined prep: x->bf16, w_attn^T->bf16, w_proj^T->bf16 ----------------
static __device__ __forceinline__ void tcvt_body(const float* in, unsigned short* out,
                                                 int R, int C, int bx, int by,
                                                 unsigned short (*tile)[65]) {
  int c0 = bx * 64, r0 = by * 64;
  int tid = threadIdx.x;
  #pragma unroll
  for (int it = 0; it < 16; ++it) {
    int idx = it * 256 + tid;
    int r = idx >> 6, c = idx & 63;
    tile[r][c] = f2bf(in[(size_t)(r0 + r) * C + c0 + c]);
  }
  __syncthreads();
  #pragma unroll
  for (int it = 0; it < 16; ++it) {
    int idx = it * 256 + tid;
    int r = idx >> 6, c = idx & 63;
    out[(size_t)(c0 + r) * R + r0 + c] = tile[c][r];
  }
}

__global__ __launch_bounds__(256) void k_prep(
    const float* __restrict__ x, unsigned short* __restrict__ x_bf,
    const float* __restrict__ w_attn, unsigned short* __restrict__ waT,
    const float* __restrict__ w_proj, unsigned short* __restrict__ wpT) {
  __shared__ unsigned short tile[64][65];
  int bid = blockIdx.x;
  if (bid < 4096) {
    int i = bid * 256 + threadIdx.x;
    float4 f = ((const float4*)x)[i];
    ushort4 o;
    o.x = f2bf(f.x); o.y = f2bf(f.y); o.z = f2bf(f.z); o.w = f2bf(f.w);
    ((ushort4*)x_bf)[i] = o;
  } else if (bid < 4096 + 768) {
    int t = bid - 4096;
    tcvt_body(w_attn, waT, 1024, 3072, t % 48, t / 48, tile);
  } else {
    int t = bid - 4096 - 768;
    tcvt_body(w_proj, wpT, 1024, 1024, t % 16, t / 16, tile);
  }
}

// ---------------- QKV GEMM: C[4096,3072] = A[4096,1024] * BT[3072,1024]^T + bias ----
// R10 K-loop (BK=32, proven 52us) + T aliased onto staging LDS (T only used
// after the loop's trailing barrier) -> 34.8KB block footprint -> 4 blocks/CU.
__global__ __launch_bounds__(256) void k_gemm_qkv(
    const unsigned short* __restrict__ A,
    const unsigned short* __restrict__ BT,
    const float* __restrict__ bias,
    float* __restrict__ outp,          // d_out base; present at +A_SIZE
    unsigned short* __restrict__ q_ws,
    unsigned short* __restrict__ kp,
    unsigned short* __restrict__ vp) {
  const int K = 1024;
  __shared__ unsigned short smem[128 * 136];   // 34.8KB union: staging (16KB) / T
  unsigned short* Asm = smem;                  // 128 x 32
  unsigned short* Bsm = smem + 128 * 32;       // 128 x 32
  unsigned short* T = smem;                    // 128 x 136 (post-loop)
  int tid = threadIdx.x;
  int lane = tid & 63, w = tid >> 6;
  int g = lane >> 4, qi = lane & 15;
  int wr = w >> 1, wc = w & 1;
  int bm = blockIdx.x & 31, bn = blockIdx.x >> 5;
  const unsigned short* Ag = A + (size_t)bm * 128 * K;
  const unsigned short* Bg = BT + (size_t)bn * 128 * K;
  int sw = (qi >> 1) & 3;
  f32x4 acc[4][4] = {};
  for (int kt = 0; kt < K; kt += 32) {
    #pragma unroll
    for (int i = 0; i < 2; ++i) {
      int j = i * 256 + tid;
      int cg = (j & 3) ^ ((j >> 3) & 3);          // pre-swizzled source chunk
      async16(Ag + (size_t)(j >> 2) * K + kt + cg * 8,
              (char*)Asm + (i * 256 + w * 64) * 16);
      async16(Bg + (size_t)(j >> 2) * K + kt + cg * 8,
              (char*)Bsm + (i * 256 + w * 64) * 16);
    }
    __syncthreads();
    short8 af[4], bf[4];
    #pragma unroll
    for (int mi = 0; mi < 4; ++mi)
      af[mi] = *(const short8*)&Asm[(wr * 64 + mi * 16 + qi) * 32 + (g ^ sw) * 8];
    #pragma unroll
    for (int ni = 0; ni < 4; ++ni)
      bf[ni] = *(const short8*)&Bsm[(wc * 64 + ni * 16 + qi) * 32 + (g ^ sw) * 8];
    #pragma unroll
    for (int mi = 0; mi < 4; ++mi)
      #pragma unroll
      for (int ni = 0; ni < 4; ++ni)
        acc[mi][ni] = __builtin_amdgcn_mfma_f32_16x16x32_bf16(af[mi], bf[ni], acc[mi][ni], 0, 0, 0);
    __syncthreads();
  }
  // ---- stage C col-major: T[n][m'] (aliases staging LDS; all reads drained) ----
  {
    int n0l = wc * 64, m0l = wr * 64;
    #pragma unroll
    for (int ni = 0; ni < 4; ++ni) {
      int nl = n0l + ni * 16 + qi;
      float bv = bias[bn * 128 + nl];
      #pragma unroll
      for (int mi = 0; mi < 4; ++mi) {
        int ml = m0l + mi * 16 + g * 4;
        uint2 pk;
        pk.x = pack_rne(acc[mi][ni][0] + bv, acc[mi][ni][1] + bv);
        pk.y = pack_rne(acc[mi][ni][2] + bv, acc[mi][ni][3] + bv);
        *(uint2*)&T[nl * 136 + TSWZ(nl, ml)] = pk;
      }
    }
  }
  __syncthreads();
  // ---- coalesced emit ----
  int third = bn >> 3;
  int b = bm >> 4;
  int s_base = (bm & 15) * 128;
  if (third == 0) {
    #pragma unroll
    for (int it = 0; it < 8; ++it) {
      int idx = it * 256 + tid;
      int sl = idx >> 4, d0 = idx & 15;
      unsigned short vv[8];
      #pragma unroll
      for (int jj = 0; jj < 8; ++jj) {
        int n = d0 * 8 + jj;
        vv[jj] = T[n * 136 + TSWZ(n, sl)];
      }
      int h = bn * 2 + (d0 >> 3);
      int din = (d0 & 7) * 8;
      *(short8*)&q_ws[(((size_t)(b * 16 + h)) * SEQ + s_base + sl) * 64 + din] = *(short8*)vv;
    }
  } else if (third == 1) {
    #pragma unroll
    for (int it = 0; it < 8; ++it) {
      int idx = it * 256 + tid;
      int sl = idx >> 4, d0 = idx & 15;
      unsigned short vv[8];
      #pragma unroll
      for (int jj = 0; jj < 8; ++jj) {
        int n = d0 * 8 + jj;
        vv[jj] = T[n * 136 + TSWZ(n, sl)];
      }
      int h = (bn - 8) * 2 + (d0 >> 3);
      int din = (d0 & 7) * 8;
      int sg = s_base + sl;
      // present[b][0][h] (fp32)
      float* pb = &outp[A_SIZE + ((((size_t)(b * 32 + h)) * SEQ + sg) * 64 + din)];
      float4 f0, f1;
      f0.x = bf2f(vv[0]); f0.y = bf2f(vv[1]); f0.z = bf2f(vv[2]); f0.w = bf2f(vv[3]);
      f1.x = bf2f(vv[4]); f1.y = bf2f(vv[5]); f1.z = bf2f(vv[6]); f1.w = bf2f(vv[7]);
      *(float4*)&pb[0] = f0;
      *(float4*)&pb[4] = f1;
      // kp fragment-packed
      int ks = sg & 63, tile = sg >> 6;
      int st = ((ks >> 5) << 1) | ((ks >> 2) & 1);
      int qik = (((ks >> 3) & 3) << 2) | (ks & 3);
      int jK = st * 2 + (din >> 5);
      int laneK = ((din >> 3) & 3) * 16 + qik;
      *(short8*)&kp[((((size_t)(b * 16 + h)) * 32 + tile) * 8 + jK) * 512 + laneK * 8] = *(short8*)vv;
    }
  } else {
    // vp: contiguous b128 LDS reads (key-runs stay contiguous under TSWZ) -> 16B stores
    #pragma unroll
    for (int it = 0; it < 8; ++it) {
      int idx = it * 256 + tid;
      int dcol = idx >> 4, k8 = idx & 15;
      short8 vv = *(const short8*)&T[dcol * 136 + TSWZ(dcol, k8 * 8)];
      int h = (bn - 16) * 2 + (dcol >> 6);
      int d = dcol & 63;
      int sg = s_base + k8 * 8;
      int tile = sg >> 6, ks0 = sg & 63;
      int jV = (d >> 4) * 2 + (ks0 >> 5);
      int laneV = ((ks0 >> 3) & 3) * 16 + (d & 15);
      *(short8*)&vp[((((size_t)(b * 16 + h)) * 32 + tile) * 8 + jV) * 512 + laneV * 8] = vv;
    }
    // present[b][1][h] (fp32)
    #pragma unroll
    for (int it = 0; it < 8; ++it) {
      int idx = it * 256 + tid;
      int sl = idx >> 4, d0 = idx & 15;
      unsigned short vv[8];
      #pragma unroll
      for (int jj = 0; jj < 8; ++jj) {
        int n = d0 * 8 + jj;
        vv[jj] = T[n * 136 + TSWZ(n, sl)];
      }
      int h = (bn - 16) * 2 + (d0 >> 3);
      int din = (d0 & 7) * 8;
      int sg = s_base + sl;
      float* pb = &outp[A_SIZE + ((((size_t)(b * 32 + 16 + h)) * SEQ + sg) * 64 + din)];
      float4 f0, f1;
      f0.x = bf2f(vv[0]); f0.y = bf2f(vv[1]); f0.z = bf2f(vv[2]); f0.w = bf2f(vv[3]);
      f1.x = bf2f(vv[4]); f1.y = bf2f(vv[5]); f1.z = bf2f(vv[6]); f1.w = bf2f(vv[7]);
      *(float4*)&pb[0] = f0;
      *(float4*)&pb[4] = f1;
    }
  }
}

// ---------------- proj GEMM: 64x64 tiles, 1024 blocks (4 blocks/CU, 16 waves/CU) ----
// Swapped orientation -> float4 stores. Wave grid 2x2, each wave 32x32.
__global__ __launch_bounds__(256) void k_gemm_proj(
    const unsigned short* __restrict__ A,
    const unsigned short* __restrict__ BT,
    const float* __restrict__ bias,
    float* __restrict__ outp) {
  const int K = 1024;
  __shared__ unsigned short Asm[64 * 32];
  __shared__ unsigned short Bsm[64 * 32];
  int tid = threadIdx.x;
  int lane = tid & 63, w = tid >> 6;
  int g = lane >> 4, qi = lane & 15;
  int wr = w >> 1, wc = w & 1;
  int bm = blockIdx.x & 63, bn = blockIdx.x >> 6;   // 64 x 16 tiles
  const unsigned short* Ag = A + (size_t)bm * 64 * K;
  const unsigned short* Bg = BT + (size_t)bn * 64 * K;
  f32x4 acc[2][2] = {};
  int row_s = tid >> 2, cp_s = tid & 3;
  int cg_s = cp_s ^ (row_s & 3);
  for (int kt = 0; kt < K; kt += 32) {
    async16(Ag + (size_t)row_s * K + kt + cg_s * 8, (char*)Asm + (size_t)tid * 16);
    async16(Bg + (size_t)row_s * K + kt + cg_s * 8, (char*)Bsm + (size_t)tid * 16);
    __syncthreads();
    short8 af[2], bf[2];
    #pragma unroll
    for (int mi = 0; mi < 2; ++mi)
      af[mi] = *(const short8*)&Asm[(wr * 32 + mi * 16 + qi) * 32 + ((g ^ (qi & 3)) * 8)];
    #pragma unroll
    for (int ni = 0; ni < 2; ++ni)
      bf[ni] = *(const short8*)&Bsm[(wc * 32 + ni * 16 + qi) * 32 + ((g ^ (qi & 3)) * 8)];
    #pragma unroll
    for (int mi = 0; mi < 2; ++mi)
      #pragma unroll
      for (int ni = 0; ni < 2; ++ni)
        acc[mi][ni] = __builtin_amdgcn_mfma_f32_16x16x32_bf16(bf[ni], af[mi], acc[mi][ni], 0, 0, 0);
    __syncthreads();
  }
  #pragma unroll
  for (int ni = 0; ni < 2; ++ni) {
    int n = bn * 64 + wc * 32 + ni * 16 + g * 4;
    float4 bv = *(const float4*)&bias[n];
    #pragma unroll
    for (int mi = 0; mi < 2; ++mi) {
      int m = bm * 64 + wr * 32 + mi * 16 + qi;
      float4 pf;
      pf.x = acc[mi][ni][0] + bv.x; pf.y = acc[mi][ni][1] + bv.y;
      pf.z = acc[mi][ni][2] + bv.z; pf.w = acc[mi][ni][3] + bv.w;
      *(float4*)&outp[(size_t)m * 1024 + n] = pf;
    }
  }
}

// ---------------- flash attention (causal), packed-fragment loads ----------------
#define CSC 0.18033688f   /* 0.125 * log2(e) */
__global__ __launch_bounds__(512, 4) void k_attn(
    const unsigned short* __restrict__ q_ws,
    const unsigned short* __restrict__ kp,
    const unsigned short* __restrict__ vp,
    unsigned short* __restrict__ a_out) {
  int bid = blockIdx.x;
  int xcd = bid & 7;
  int jb = bid >> 3;                 // 0..63
  int bh = xcd * 4 + (jb & 3);       // 4 heads per XCD -> K/V L2-resident
  int pairidx = jb >> 2;             // 0..15
  int tid = threadIdx.x, lane = tid & 63, w = tid >> 6;
  int g = lane >> 4, qi = lane & 15;
  int tilesel = w >> 2, wl = w & 3;
  int q0 = (tilesel ? pairidx : (31 - pairidx)) * 64;
  int qw = q0 + wl * 16;
  int qrow = qw + qi;
  const unsigned short* Qb = q_ws + (size_t)bh * SEQ * 64;
  const unsigned short* Kp = kp + (size_t)bh * SEQ * 64;   // 32 tiles * 4096 shorts
  const unsigned short* Vp = vp + (size_t)bh * SEQ * 64;

  short8 qf0 = *(const short8*)&Qb[(size_t)qrow * 64 + g * 8];
  short8 qf1 = *(const short8*)&Qb[(size_t)qrow * 64 + g * 8 + 32];

  f32x4 oacc[4] = {};
  float m2 = -1.0e30f, l_run = 0.f;   // per-lane partial sum over this lane's keys
  f32x4 z = {};
  int nfull = qw >> 6;

  for (int t = 0; t <= nfull; ++t) {
    const unsigned short* Kt = Kp + (size_t)t * 4096;
    const unsigned short* Vt = Vp + (size_t)t * 4096;
    // 16 contiguous 1KB wave loads
    short8 kf[4][2];
    #pragma unroll
    for (int st = 0; st < 4; ++st) {
      kf[st][0] = *(const short8*)&Kt[(st * 2 + 0) * 512 + lane * 8];
      kf[st][1] = *(const short8*)&Kt[(st * 2 + 1) * 512 + lane * 8];
    }
    short8 vf0[4], vf1[4];
    #pragma unroll
    for (int dt = 0; dt < 4; ++dt) {
      vf0[dt] = *(const short8*)&Vt[(dt * 2 + 0) * 512 + lane * 8];
      vf1[dt] = *(const short8*)&Vt[(dt * 2 + 1) * 512 + lane * 8];
    }
    f32x4 sa[4];
    #pragma unroll
    for (int st = 0; st < 4; ++st) {
      sa[st] = __builtin_amdgcn_mfma_f32_16x16x32_bf16(kf[st][0], qf0, z, 0, 0, 0);
      sa[st] = __builtin_amdgcn_mfma_f32_16x16x32_bf16(kf[st][1], qf1, sa[st], 0, 0, 0);
    }
    // lane (g,qi): sa[st][r] = score for q-row qrow, key t*64+(st>>1)*32+(st&1)*4+g*8+r
    float tm = -1.0e30f;
    if (t == nfull) {   // wave-uniform masked tail tile
      #pragma unroll
      for (int st = 0; st < 4; ++st)
        #pragma unroll
        for (int r = 0; r < 4; ++r) {
          int key = t * 64 + (st >> 1) * 32 + (st & 1) * 4 + g * 8 + r;
          float v = (key <= qrow) ? sa[st][r] * CSC : -1.0e30f;
          sa[st][r] = v;
          tm = fmaxf(tm, v);
        }
    } else {
      #pragma unroll
      for (int st = 0; st < 4; ++st)
        #pragma unroll
        for (int r = 0; r < 4; ++r) {
          sa[st][r] *= CSC;
          tm = fmaxf(tm, sa[st][r]);
        }
    }
    if (!__all(tm - m2 <= 4.0f)) {      // defer-max (partial-max bound suffices)
      tm = fmaxf(tm, __shfl_xor(tm, 16, 64));
      tm = fmaxf(tm, __shfl_xor(tm, 32, 64));
      float mn = fmaxf(m2, tm);
      float alpha = exp2f(m2 - mn);
      l_run *= alpha;
      #pragma unroll
      for (int dt = 0; dt < 4; ++dt)
        #pragma unroll
        for (int r = 0; r < 4; ++r) oacc[dt][r] *= alpha;
      m2 = mn;
    }
    float ps = 0.f;
    union { uint32_t u[4]; short8 s; } pb0, pb1;
    #pragma unroll
    for (int st = 0; st < 4; ++st) {
      float p0 = exp2f(sa[st][0] - m2);
      float p1 = exp2f(sa[st][1] - m2);
      float p2 = exp2f(sa[st][2] - m2);
      float p3 = exp2f(sa[st][3] - m2);
      ps += (p0 + p1) + (p2 + p3);
      uint32_t lo = pack_bf2(p0, p1), hi = pack_bf2(p2, p3);
      if (st < 2) { pb0.u[st * 2] = lo; pb0.u[st * 2 + 1] = hi; }
      else        { pb1.u[(st - 2) * 2] = lo; pb1.u[(st - 2) * 2 + 1] = hi; }
    }
    l_run += ps;
    #pragma unroll
    for (int dt = 0; dt < 4; ++dt) {
      oacc[dt] = __builtin_amdgcn_mfma_f32_16x16x32_bf16(vf0[dt], pb0.s, oacc[dt], 0, 0, 0);
      oacc[dt] = __builtin_amdgcn_mfma_f32_16x16x32_bf16(vf1[dt], pb1.s, oacc[dt], 0, 0, 0);
    }
  }

  // one-time l reduce across the 4 lane-groups of each q-row
  l_run += __shfl_xor(l_run, 16, 64);
  l_run += __shfl_xor(l_run, 32, 64);
  float inv = 1.0f / l_run;
  int b = bh >> 4, h = bh & 15;
  size_t rowbase = ((size_t)(b * SEQ + qw + qi)) * 1024 + h * 64;
  #pragma unroll
  for (int dt = 0; dt < 4; ++dt) {
    ushort4 o;
    o.x = f2bf(oacc[dt][0] * inv);
    o.y = f2bf(oacc[dt][1] * inv);
    o.z = f2bf(oacc[dt][2] * inv);
    o.w = f2bf(oacc[dt][3] * inv);
    *(ushort4*)&a_out[rowbase + dt * 16 + g * 4] = o;
  }
}

// ---------------- launch ----------------
extern "C" void kernel_launch(void* const* d_in, const int* in_sizes, int n_in,
                              void* d_out, int out_size, void* d_ws, size_t ws_size,
                              hipStream_t stream) {
  const float* x      = (const float*)d_in[0];
  const float* w_attn = (const float*)d_in[1];
  const float* b_attn = (const float*)d_in[2];
  const float* w_proj = (const float*)d_in[3];
  const float* b_proj = (const float*)d_in[4];
  float* out = (float*)d_out;
  char* ws = (char*)d_ws;
  // ws layout (48 MB total)
  unsigned short* x_bf = (unsigned short*)(ws);               //  8 MB
  unsigned short* waT  = (unsigned short*)(ws + 8388608);     //  6 MB
  unsigned short* wpT  = (unsigned short*)(ws + 14680064);    //  2 MB
  unsigned short* q_ws = (unsigned short*)(ws + 16777216);    //  8 MB
  unsigned short* kp   = (unsigned short*)(ws + 25165824);    //  8 MB (fragment-packed K)
  unsigned short* vp   = (unsigned short*)(ws + 33554432);    //  8 MB (fragment-packed V)
  unsigned short* a_ws = (unsigned short*)(ws + 41943040);    //  8 MB

  hipLaunchKernelGGL(k_prep, dim3(4096 + 768 + 256), dim3(256), 0, stream,
                     x, x_bf, w_attn, waT, w_proj, wpT);
  hipLaunchKernelGGL(k_gemm_qkv, dim3(768), dim3(256), 0, stream,
                     x_bf, waT, b_attn, out, q_ws, kp, vp);
  hipLaunchKernelGGL(k_attn, dim3(512), dim3(512), 0, stream, q_ws, kp, vp, a_ws);
  hipLaunchKernelGGL(k_gemm_proj, dim3(1024), dim3(256), 0, stream, a_ws, wpT, b_proj, out);
}

// Round 13
// 106.118 us; speedup vs baseline: 1.1065x; 1.0042x over previous
//
#include <hip/hip_runtime.h>
#include <stdint.h>

// Problem dims (fixed): B=2, S=2048, D=1024, H=16, d_head=64
#define SEQ 2048
#define A_SIZE 4194304   // 2*2048*1024 floats (output 'a'), present follows

typedef short short8 __attribute__((ext_vector_type(8)));
typedef float f32x4 __attribute__((ext_vector_type(4)));

#define AS1 __attribute__((address_space(1)))
#define AS3 __attribute__((address_space(3)))

static __device__ __forceinline__ void async16(const void* g, void* l) {
  __builtin_amdgcn_global_load_lds((const AS1 uint32_t*)g, (AS3 uint32_t*)l, 16, 0, 0);
}

static __device__ __forceinline__ unsigned short f2bf(float f) {
  union { float f; uint32_t u; } v; v.f = f;
  uint32_t u = v.u;
  return (unsigned short)((u + 0x7FFFu + ((u >> 16) & 1u)) >> 16);
}

static __device__ __forceinline__ uint32_t fbits(float f) {
  union { float f; uint32_t u; } v; v.f = f;
  return v.u;
}

static __device__ __forceinline__ float bf2f(unsigned short b) {
  union { uint32_t u; float f; } c; c.u = ((uint32_t)b) << 16;
  return c.f;
}

// pack two floats to two truncated bf16 in one u32 (used for P in attn only)
static __device__ __forceinline__ uint32_t pack_bf2(float p0, float p1) {
  return __builtin_amdgcn_perm(fbits(p1), fbits(p0), 0x07060302u);
}

// RNE pack for GEMM outputs
static __device__ __forceinline__ uint32_t pack_rne(float a, float b) {
  return (uint32_t)f2bf(a) | ((uint32_t)f2bf(b) << 16);
}

// T-stage swizzle: m' = m ^ ((n>>3 & 7)<<3). Multiple of 8 => keeps 4- and
// 8-short runs contiguous; spreads the emit's d0-strided reads across banks.
#define TSWZ(n, m) ((m) ^ ((((n) >> 3) & 7) << 3))

// ---------------- combined prep: x->bf16, w_attn^T->bf16, w_proj^T->bf16 ----------------
static __device__ __forceinline__ void tcvt_body(const float* in, unsigned short* out,
                                                 int R, int C, int bx, int by,
                                                 unsigned short (*tile)[65]) {
  int c0 = bx * 64, r0 = by * 64;
  int tid = threadIdx.x;
  #pragma unroll
  for (int it = 0; it < 16; ++it) {
    int idx = it * 256 + tid;
    int r = idx >> 6, c = idx & 63;
    tile[r][c] = f2bf(in[(size_t)(r0 + r) * C + c0 + c]);
  }
  __syncthreads();
  #pragma unroll
  for (int it = 0; it < 16; ++it) {
    int idx = it * 256 + tid;
    int r = idx >> 6, c = idx & 63;
    out[(size_t)(c0 + r) * R + r0 + c] = tile[c][r];
  }
}

__global__ __launch_bounds__(256) void k_prep(
    const float* __restrict__ x, unsigned short* __restrict__ x_bf,
    const float* __restrict__ w_attn, unsigned short* __restrict__ waT,
    const float* __restrict__ w_proj, unsigned short* __restrict__ wpT) {
  __shared__ unsigned short tile[64][65];
  int bid = blockIdx.x;
  if (bid < 4096) {
    int i = bid * 256 + threadIdx.x;
    float4 f = ((const float4*)x)[i];
    ushort4 o;
    o.x = f2bf(f.x); o.y = f2bf(f.y); o.z = f2bf(f.z); o.w = f2bf(f.w);
    ((ushort4*)x_bf)[i] = o;
  } else if (bid < 4096 + 768) {
    int t = bid - 4096;
    tcvt_body(w_attn, waT, 1024, 3072, t % 48, t / 48, tile);
  } else {
    int t = bid - 4096 - 768;
    tcvt_body(w_proj, wpT, 1024, 1024, t % 16, t / 16, tile);
  }
}

// ---------------- QKV GEMM: C[4096,3072] = A[4096,1024] * BT[3072,1024]^T + bias ----
// R12 structure + XCD-chunked block remap (T1): each XCD owns 4 bm (2MB A,
// L2-resident, reused 24x); B panels fetched once per XCD, reused 4x.
__global__ __launch_bounds__(256) void k_gemm_qkv(
    const unsigned short* __restrict__ A,
    const unsigned short* __restrict__ BT,
    const float* __restrict__ bias,
    float* __restrict__ outp,          // d_out base; present at +A_SIZE
    unsigned short* __restrict__ q_ws,
    unsigned short* __restrict__ kp,
    unsigned short* __restrict__ vp) {
  const int K = 1024;
  __shared__ unsigned short smem[128 * 136];   // 34.8KB union: staging (16KB) / T
  unsigned short* Asm = smem;                  // 128 x 32
  unsigned short* Bsm = smem + 128 * 32;       // 128 x 32
  unsigned short* T = smem;                    // 128 x 136 (post-loop)
  int tid = threadIdx.x;
  int lane = tid & 63, w = tid >> 6;
  int g = lane >> 4, qi = lane & 15;
  int wr = w >> 1, wc = w & 1;
  // XCD-chunked remap: xcd = bid%8 (dispatch round-robin), 96 blocks per XCD.
  int bid = blockIdx.x;
  int xcd = bid & 7, jj_ = bid >> 3;          // jj_ in [0,96)
  int bm = xcd * 4 + (jj_ & 3);               // 4 A-panels per XCD (2MB, resident)
  int bn = jj_ >> 2;                          // 0..23, B panel streams
  const unsigned short* Ag = A + (size_t)bm * 128 * K;
  const unsigned short* Bg = BT + (size_t)bn * 128 * K;
  int sw = (qi >> 1) & 3;
  f32x4 acc[4][4] = {};
  for (int kt = 0; kt < K; kt += 32) {
    #pragma unroll
    for (int i = 0; i < 2; ++i) {
      int j = i * 256 + tid;
      int cg = (j & 3) ^ ((j >> 3) & 3);          // pre-swizzled source chunk
      async16(Ag + (size_t)(j >> 2) * K + kt + cg * 8,
              (char*)Asm + (i * 256 + w * 64) * 16);
      async16(Bg + (size_t)(j >> 2) * K + kt + cg * 8,
              (char*)Bsm + (i * 256 + w * 64) * 16);
    }
    __syncthreads();
    short8 af[4], bf[4];
    #pragma unroll
    for (int mi = 0; mi < 4; ++mi)
      af[mi] = *(const short8*)&Asm[(wr * 64 + mi * 16 + qi) * 32 + (g ^ sw) * 8];
    #pragma unroll
    for (int ni = 0; ni < 4; ++ni)
      bf[ni] = *(const short8*)&Bsm[(wc * 64 + ni * 16 + qi) * 32 + (g ^ sw) * 8];
    #pragma unroll
    for (int mi = 0; mi < 4; ++mi)
      #pragma unroll
      for (int ni = 0; ni < 4; ++ni)
        acc[mi][ni] = __builtin_amdgcn_mfma_f32_16x16x32_bf16(af[mi], bf[ni], acc[mi][ni], 0, 0, 0);
    __syncthreads();
  }
  // ---- stage C col-major: T[n][m'] (aliases staging LDS; all reads drained) ----
  {
    int n0l = wc * 64, m0l = wr * 64;
    #pragma unroll
    for (int ni = 0; ni < 4; ++ni) {
      int nl = n0l + ni * 16 + qi;
      float bv = bias[bn * 128 + nl];
      #pragma unroll
      for (int mi = 0; mi < 4; ++mi) {
        int ml = m0l + mi * 16 + g * 4;
        uint2 pk;
        pk.x = pack_rne(acc[mi][ni][0] + bv, acc[mi][ni][1] + bv);
        pk.y = pack_rne(acc[mi][ni][2] + bv, acc[mi][ni][3] + bv);
        *(uint2*)&T[nl * 136 + TSWZ(nl, ml)] = pk;
      }
    }
  }
  __syncthreads();
  // ---- coalesced emit ----
  int third = bn >> 3;
  int b = bm >> 4;
  int s_base = (bm & 15) * 128;
  if (third == 0) {
    #pragma unroll
    for (int it = 0; it < 8; ++it) {
      int idx = it * 256 + tid;
      int sl = idx >> 4, d0 = idx & 15;
      unsigned short vv[8];
      #pragma unroll
      for (int jj = 0; jj < 8; ++jj) {
        int n = d0 * 8 + jj;
        vv[jj] = T[n * 136 + TSWZ(n, sl)];
      }
      int h = bn * 2 + (d0 >> 3);
      int din = (d0 & 7) * 8;
      *(short8*)&q_ws[(((size_t)(b * 16 + h)) * SEQ + s_base + sl) * 64 + din] = *(short8*)vv;
    }
  } else if (third == 1) {
    #pragma unroll
    for (int it = 0; it < 8; ++it) {
      int idx = it * 256 + tid;
      int sl = idx >> 4, d0 = idx & 15;
      unsigned short vv[8];
      #pragma unroll
      for (int jj = 0; jj < 8; ++jj) {
        int n = d0 * 8 + jj;
        vv[jj] = T[n * 136 + TSWZ(n, sl)];
      }
      int h = (bn - 8) * 2 + (d0 >> 3);
      int din = (d0 & 7) * 8;
      int sg = s_base + sl;
      // present[b][0][h] (fp32)
      float* pb = &outp[A_SIZE + ((((size_t)(b * 32 + h)) * SEQ + sg) * 64 + din)];
      float4 f0, f1;
      f0.x = bf2f(vv[0]); f0.y = bf2f(vv[1]); f0.z = bf2f(vv[2]); f0.w = bf2f(vv[3]);
      f1.x = bf2f(vv[4]); f1.y = bf2f(vv[5]); f1.z = bf2f(vv[6]); f1.w = bf2f(vv[7]);
      *(float4*)&pb[0] = f0;
      *(float4*)&pb[4] = f1;
      // kp fragment-packed
      int ks = sg & 63, tile = sg >> 6;
      int st = ((ks >> 5) << 1) | ((ks >> 2) & 1);
      int qik = (((ks >> 3) & 3) << 2) | (ks & 3);
      int jK = st * 2 + (din >> 5);
      int laneK = ((din >> 3) & 3) * 16 + qik;
      *(short8*)&kp[((((size_t)(b * 16 + h)) * 32 + tile) * 8 + jK) * 512 + laneK * 8] = *(short8*)vv;
    }
  } else {
    // vp: contiguous b128 LDS reads (key-runs stay contiguous under TSWZ) -> 16B stores
    #pragma unroll
    for (int it = 0; it < 8; ++it) {
      int idx = it * 256 + tid;
      int dcol = idx >> 4, k8 = idx & 15;
      short8 vv = *(const short8*)&T[dcol * 136 + TSWZ(dcol, k8 * 8)];
      int h = (bn - 16) * 2 + (dcol >> 6);
      int d = dcol & 63;
      int sg = s_base + k8 * 8;
      int tile = sg >> 6, ks0 = sg & 63;
      int jV = (d >> 4) * 2 + (ks0 >> 5);
      int laneV = ((ks0 >> 3) & 3) * 16 + (d & 15);
      *(short8*)&vp[((((size_t)(b * 16 + h)) * 32 + tile) * 8 + jV) * 512 + laneV * 8] = vv;
    }
    // present[b][1][h] (fp32)
    #pragma unroll
    for (int it = 0; it < 8; ++it) {
      int idx = it * 256 + tid;
      int sl = idx >> 4, d0 = idx & 15;
      unsigned short vv[8];
      #pragma unroll
      for (int jj = 0; jj < 8; ++jj) {
        int n = d0 * 8 + jj;
        vv[jj] = T[n * 136 + TSWZ(n, sl)];
      }
      int h = (bn - 16) * 2 + (d0 >> 3);
      int din = (d0 & 7) * 8;
      int sg = s_base + sl;
      float* pb = &outp[A_SIZE + ((((size_t)(b * 32 + 16 + h)) * SEQ + sg) * 64 + din)];
      float4 f0, f1;
      f0.x = bf2f(vv[0]); f0.y = bf2f(vv[1]); f0.z = bf2f(vv[2]); f0.w = bf2f(vv[3]);
      f1.x = bf2f(vv[4]); f1.y = bf2f(vv[5]); f1.z = bf2f(vv[6]); f1.w = bf2f(vv[7]);
      *(float4*)&pb[0] = f0;
      *(float4*)&pb[4] = f1;
    }
  }
}

// ---------------- proj GEMM: 64x64 tiles, 1024 blocks, XCD-chunked remap ----
__global__ __launch_bounds__(256) void k_gemm_proj(
    const unsigned short* __restrict__ A,
    const unsigned short* __restrict__ BT,
    const float* __restrict__ bias,
    float* __restrict__ outp) {
  const int K = 1024;
  __shared__ unsigned short Asm[64 * 32];
  __shared__ unsigned short Bsm[64 * 32];
  int tid = threadIdx.x;
  int lane = tid & 63, w = tid >> 6;
  int g = lane >> 4, qi = lane & 15;
  int wr = w >> 1, wc = w & 1;
  int bid = blockIdx.x;
  int xcd = bid & 7, jj_ = bid >> 3;          // jj_ in [0,128)
  int bm = xcd * 8 + (jj_ & 7);               // 8 A-panels per XCD (1MB, resident)
  int bn = jj_ >> 3;                          // 0..15
  const unsigned short* Ag = A + (size_t)bm * 64 * K;
  const unsigned short* Bg = BT + (size_t)bn * 64 * K;
  f32x4 acc[2][2] = {};
  int row_s = tid >> 2, cp_s = tid & 3;
  int cg_s = cp_s ^ (row_s & 3);
  for (int kt = 0; kt < K; kt += 32) {
    async16(Ag + (size_t)row_s * K + kt + cg_s * 8, (char*)Asm + (size_t)tid * 16);
    async16(Bg + (size_t)row_s * K + kt + cg_s * 8, (char*)Bsm + (size_t)tid * 16);
    __syncthreads();
    short8 af[2], bf[2];
    #pragma unroll
    for (int mi = 0; mi < 2; ++mi)
      af[mi] = *(const short8*)&Asm[(wr * 32 + mi * 16 + qi) * 32 + ((g ^ (qi & 3)) * 8)];
    #pragma unroll
    for (int ni = 0; ni < 2; ++ni)
      bf[ni] = *(const short8*)&Bsm[(wc * 32 + ni * 16 + qi) * 32 + ((g ^ (qi & 3)) * 8)];
    #pragma unroll
    for (int mi = 0; mi < 2; ++mi)
      #pragma unroll
      for (int ni = 0; ni < 2; ++ni)
        acc[mi][ni] = __builtin_amdgcn_mfma_f32_16x16x32_bf16(bf[ni], af[mi], acc[mi][ni], 0, 0, 0);
    __syncthreads();
  }
  #pragma unroll
  for (int ni = 0; ni < 2; ++ni) {
    int n = bn * 64 + wc * 32 + ni * 16 + g * 4;
    float4 bv = *(const float4*)&bias[n];
    #pragma unroll
    for (int mi = 0; mi < 2; ++mi) {
      int m = bm * 64 + wr * 32 + mi * 16 + qi;
      float4 pf;
      pf.x = acc[mi][ni][0] + bv.x; pf.y = acc[mi][ni][1] + bv.y;
      pf.z = acc[mi][ni][2] + bv.z; pf.w = acc[mi][ni][3] + bv.w;
      *(float4*)&outp[(size_t)m * 1024 + n] = pf;
    }
  }
}

// ---------------- flash attention (causal), packed-fragment loads ----------------
#define CSC 0.18033688f   /* 0.125 * log2(e) */
__global__ __launch_bounds__(512, 4) void k_attn(
    const unsigned short* __restrict__ q_ws,
    const unsigned short* __restrict__ kp,
    const unsigned short* __restrict__ vp,
    unsigned short* __restrict__ a_out) {
  int bid = blockIdx.x;
  int xcd = bid & 7;
  int jb = bid >> 3;                 // 0..63
  int bh = xcd * 4 + (jb & 3);       // 4 heads per XCD -> K/V L2-resident
  int pairidx = jb >> 2;             // 0..15
  int tid = threadIdx.x, lane = tid & 63, w = tid >> 6;
  int g = lane >> 4, qi = lane & 15;
  int tilesel = w >> 2, wl = w & 3;
  int q0 = (tilesel ? pairidx : (31 - pairidx)) * 64;
  int qw = q0 + wl * 16;
  int qrow = qw + qi;
  const unsigned short* Qb = q_ws + (size_t)bh * SEQ * 64;
  const unsigned short* Kp = kp + (size_t)bh * SEQ * 64;   // 32 tiles * 4096 shorts
  const unsigned short* Vp = vp + (size_t)bh * SEQ * 64;

  short8 qf0 = *(const short8*)&Qb[(size_t)qrow * 64 + g * 8];
  short8 qf1 = *(const short8*)&Qb[(size_t)qrow * 64 + g * 8 + 32];

  f32x4 oacc[4] = {};
  float m2 = -1.0e30f, l_run = 0.f;   // per-lane partial sum over this lane's keys
  f32x4 z = {};
  int nfull = qw >> 6;

  for (int t = 0; t <= nfull; ++t) {
    const unsigned short* Kt = Kp + (size_t)t * 4096;
    const unsigned short* Vt = Vp + (size_t)t * 4096;
    // 16 contiguous 1KB wave loads
    short8 kf[4][2];
    #pragma unroll
    for (int st = 0; st < 4; ++st) {
      kf[st][0] = *(const short8*)&Kt[(st * 2 + 0) * 512 + lane * 8];
      kf[st][1] = *(const short8*)&Kt[(st * 2 + 1) * 512 + lane * 8];
    }
    short8 vf0[4], vf1[4];
    #pragma unroll
    for (int dt = 0; dt < 4; ++dt) {
      vf0[dt] = *(const short8*)&Vt[(dt * 2 + 0) * 512 + lane * 8];
      vf1[dt] = *(const short8*)&Vt[(dt * 2 + 1) * 512 + lane * 8];
    }
    f32x4 sa[4];
    #pragma unroll
    for (int st = 0; st < 4; ++st) {
      sa[st] = __builtin_amdgcn_mfma_f32_16x16x32_bf16(kf[st][0], qf0, z, 0, 0, 0);
      sa[st] = __builtin_amdgcn_mfma_f32_16x16x32_bf16(kf[st][1], qf1, sa[st], 0, 0, 0);
    }
    // lane (g,qi): sa[st][r] = score for q-row qrow, key t*64+(st>>1)*32+(st&1)*4+g*8+r
    float tm = -1.0e30f;
    if (t == nfull) {   // wave-uniform masked tail tile
      #pragma unroll
      for (int st = 0; st < 4; ++st)
        #pragma unroll
        for (int r = 0; r < 4; ++r) {
          int key = t * 64 + (st >> 1) * 32 + (st & 1) * 4 + g * 8 + r;
          float v = (key <= qrow) ? sa[st][r] * CSC : -1.0e30f;
          sa[st][r] = v;
          tm = fmaxf(tm, v);
        }
    } else {
      #pragma unroll
      for (int st = 0; st < 4; ++st)
        #pragma unroll
        for (int r = 0; r < 4; ++r) {
          sa[st][r] *= CSC;
          tm = fmaxf(tm, sa[st][r]);
        }
    }
    if (!__all(tm - m2 <= 4.0f)) {      // defer-max (partial-max bound suffices)
      tm = fmaxf(tm, __shfl_xor(tm, 16, 64));
      tm = fmaxf(tm, __shfl_xor(tm, 32, 64));
      float mn = fmaxf(m2, tm);
      float alpha = exp2f(m2 - mn);
      l_run *= alpha;
      #pragma unroll
      for (int dt = 0; dt < 4; ++dt)
        #pragma unroll
        for (int r = 0; r < 4; ++r) oacc[dt][r] *= alpha;
      m2 = mn;
    }
    float ps = 0.f;
    union { uint32_t u[4]; short8 s; } pb0, pb1;
    #pragma unroll
    for (int st = 0; st < 4; ++st) {
      float p0 = exp2f(sa[st][0] - m2);
      float p1 = exp2f(sa[st][1] - m2);
      float p2 = exp2f(sa[st][2] - m2);
      float p3 = exp2f(sa[st][3] - m2);
      ps += (p0 + p1) + (p2 + p3);
      uint32_t lo = pack_bf2(p0, p1), hi = pack_bf2(p2, p3);
      if (st < 2) { pb0.u[st * 2] = lo; pb0.u[st * 2 + 1] = hi; }
      else        { pb1.u[(st - 2) * 2] = lo; pb1.u[(st - 2) * 2 + 1] = hi; }
    }
    l_run += ps;
    #pragma unroll
    for (int dt = 0; dt < 4; ++dt) {
      oacc[dt] = __builtin_amdgcn_mfma_f32_16x16x32_bf16(vf0[dt], pb0.s, oacc[dt], 0, 0, 0);
      oacc[dt] = __builtin_amdgcn_mfma_f32_16x16x32_bf16(vf1[dt], pb1.s, oacc[dt], 0, 0, 0);
    }
  }

  // one-time l reduce across the 4 lane-groups of each q-row
  l_run += __shfl_xor(l_run, 16, 64);
  l_run += __shfl_xor(l_run, 32, 64);
  float inv = 1.0f / l_run;
  int b = bh >> 4, h = bh & 15;
  size_t rowbase = ((size_t)(b * SEQ + qw + qi)) * 1024 + h * 64;
  #pragma unroll
  for (int dt = 0; dt < 4; ++dt) {
    ushort4 o;
    o.x = f2bf(oacc[dt][0] * inv);
    o.y = f2bf(oacc[dt][1] * inv);
    o.z = f2bf(oacc[dt][2] * inv);
    o.w = f2bf(oacc[dt][3] * inv);
    *(ushort4*)&a_out[rowbase + dt * 16 + g * 4] = o;
  }
}

// ---------------- launch ----------------
extern "C" void kernel_launch(void* const* d_in, const int* in_sizes, int n_in,
                              void* d_out, int out_size, void* d_ws, size_t ws_size,
                              hipStream_t stream) {
  const float* x      = (const float*)d_in[0];
  const float* w_attn = (const float*)d_in[1];
  const float* b_attn = (const float*)d_in[2];
  const float* w_proj = (const float*)d_in[3];
  const float* b_proj = (const float*)d_in[4];
  float* out = (float*)d_out;
  char* ws = (char*)d_ws;
  // ws layout (48 MB total)
  unsigned short* x_bf = (unsigned short*)(ws);               //  8 MB
  unsigned short* waT  = (unsigned short*)(ws + 8388608);     //  6 MB
  unsigned short* wpT  = (unsigned short*)(ws + 14680064);    //  2 MB
  unsigned short* q_ws = (unsigned short*)(ws + 16777216);    //  8 MB
  unsigned short* kp   = (unsigned short*)(ws + 25165824);    //  8 MB (fragment-packed K)
  unsigned short* vp   = (unsigned short*)(ws + 33554432);    //  8 MB (fragment-packed V)
  unsigned short* a_ws = (unsigned short*)(ws + 41943040);    //  8 MB

  hipLaunchKernelGGL(k_prep, dim3(4096 + 768 + 256), dim3(256), 0, stream,
                     x, x_bf, w_attn, waT, w_proj, wpT);
  hipLaunchKernelGGL(k_gemm_qkv, dim3(768), dim3(256), 0, stream,
                     x_bf, waT, b_attn, out, q_ws, kp, vp);
  hipLaunchKernelGGL(k_attn, dim3(512), dim3(512), 0, stream, q_ws, kp, vp, a_ws);
  hipLaunchKernelGGL(k_gemm_proj, dim3(1024), dim3(256), 0, stream, a_ws, wpT, b_proj, out);
}